// Round 2
// baseline (157.249 us; speedup 1.0000x reference)
//
#include <hip/hip_runtime.h>
#include <math.h>

// PopulationEncoder: spikes[b,f,n,t] = (u[b,f,n,t] < rate[b,f,n]) ? 1.0f : 0.0f
//   rate = exp(-(x[b,f]-c[n])^2 / (2*sigma^2)) * max_rate / 1000
//   u    = jax.random.uniform(key(1), (64,128,100,100))
//
// JAX >= 0.5 defaults jax_threefry_partitionable=True:
//   counts1, counts2 = iota_2x32_shape(shape)   // 64-bit index split hi/lo
//   bits1, bits2 = threefry2x32(key, counts1, counts2)
//   bits = bits1 ^ bits2                        // 32-bit draw per element
// size = 81,920,000 < 2^32  ->  counts1 = 0, counts2 = p (flat row-major index).
// key(1) -> (k1,k2) = (0,1).
//
// u = bitcast((bits>>9)|0x3f800000) - 1.0 = (bits>>9) * 2^-23 exactly, so
// u < rate  <=>  (bits>>9) < ceil(rate * 2^23)   (rate*2^23 is an exact scale).

#define TOTAL_N 81920000u
#define ELEMS_PER_BLOCK 2048u   // 256 threads x 8 elems (two row-safe quads)

__device__ __forceinline__ uint32_t rotl(uint32_t x, uint32_t d) {
  return (x << d) | (x >> (32u - d));
}

__device__ __forceinline__ void tf_round(uint32_t& x0, uint32_t& x1, uint32_t r) {
  x0 += x1;
  x1 = rotl(x1, r);
  x1 ^= x0;
}

// Threefry-2x32, 20 rounds, key=(0,1), counter=(0,p). Returns y0 ^ y1.
__device__ __forceinline__ uint32_t threefry_xor(uint32_t p) {
  const uint32_t ks0 = 0u, ks1 = 1u, ks2 = 0x1BD11BDBu; // 0x1BD11BDA ^ 0 ^ 1
  uint32_t x0 = 0u + ks0;   // c0 = 0
  uint32_t x1 = p + ks1;
  tf_round(x0, x1, 13); tf_round(x0, x1, 15); tf_round(x0, x1, 26); tf_round(x0, x1, 6);
  x0 += ks1; x1 += ks2 + 1u;
  tf_round(x0, x1, 17); tf_round(x0, x1, 29); tf_round(x0, x1, 16); tf_round(x0, x1, 24);
  x0 += ks2; x1 += ks0 + 2u;
  tf_round(x0, x1, 13); tf_round(x0, x1, 15); tf_round(x0, x1, 26); tf_round(x0, x1, 6);
  x0 += ks0; x1 += ks1 + 3u;
  tf_round(x0, x1, 17); tf_round(x0, x1, 29); tf_round(x0, x1, 16); tf_round(x0, x1, 24);
  x0 += ks1; x1 += ks2 + 4u;
  tf_round(x0, x1, 13); tf_round(x0, x1, 15); tf_round(x0, x1, 26); tf_round(x0, x1, 6);
  x0 += ks2; x1 += ks0 + 5u;
  return x0 ^ x1;
}

__global__ __launch_bounds__(256) void popenc_kernel(
    const float* __restrict__ x,            // [64,128]
    const float* __restrict__ centers,      // [100]
    const float* __restrict__ log_sigma,    // [1]
    const float* __restrict__ log_max_rate, // [1]
    float* __restrict__ out) {              // [64,128,100,100] flat
  // Block covers elements [B0, B0+2048). row = p/100 = (b*128+f)*100+n.
  // 2048 elems span <= 22 rows.
  __shared__ uint32_t sK[22];  // ceil(rate*2^23) per row

  const uint32_t B0 = blockIdx.x * ELEMS_PER_BLOCK;
  const uint32_t rowFirst = B0 / 100u;
  const uint32_t rowLast  = (B0 + ELEMS_PER_BLOCK - 1u) / 100u;
  const uint32_t nRows    = rowLast - rowFirst + 1u;  // <= 22
  const uint32_t tid = threadIdx.x;

  if (tid < nRows) {
    const uint32_t row = rowFirst + tid;
    // Replicate reference fp32 op order; exp via double -> correctly-rounded f32.
    const float sigma = (float)exp((double)log_sigma[0]);
    const float mrate = (float)exp((double)log_max_rate[0]);
    const float s2    = __fmul_rn(__fmul_rn(2.0f, sigma), sigma);
    const uint32_t xidx = row / 100u;   // b*128+f
    const uint32_t n    = row % 100u;
    const float d    = __fsub_rn(x[xidx], centers[n]);
    const float num  = __fmul_rn(d, d);
    const float arg  = __fdiv_rn(-num, s2);
    const float resp = (float)exp((double)arg);
    const float fr   = __fdiv_rn(__fmul_rn(resp, mrate), 1000.0f);
    const float rs   = __fmul_rn(fr, 8388608.0f); // * 2^23, exact
    sK[tid] = (uint32_t)ceilf(rs);
  }
  __syncthreads();

  // Two quads per thread; 4 | 100 so a quad never crosses a row boundary.
  const uint32_t pA = B0 + tid * 4u;
  const uint32_t pB = pA + 1024u;
  const uint32_t KA = sK[(pA / 100u) - rowFirst];
  const uint32_t KB = sK[(pB / 100u) - rowFirst];

  float4 qa, qb;
  qa.x = ((threefry_xor(pA + 0u) >> 9) < KA) ? 1.0f : 0.0f;
  qa.y = ((threefry_xor(pA + 1u) >> 9) < KA) ? 1.0f : 0.0f;
  qa.z = ((threefry_xor(pA + 2u) >> 9) < KA) ? 1.0f : 0.0f;
  qa.w = ((threefry_xor(pA + 3u) >> 9) < KA) ? 1.0f : 0.0f;
  qb.x = ((threefry_xor(pB + 0u) >> 9) < KB) ? 1.0f : 0.0f;
  qb.y = ((threefry_xor(pB + 1u) >> 9) < KB) ? 1.0f : 0.0f;
  qb.z = ((threefry_xor(pB + 2u) >> 9) < KB) ? 1.0f : 0.0f;
  qb.w = ((threefry_xor(pB + 3u) >> 9) < KB) ? 1.0f : 0.0f;

  *reinterpret_cast<float4*>(out + pA) = qa;
  *reinterpret_cast<float4*>(out + pB) = qb;
}

extern "C" void kernel_launch(void* const* d_in, const int* in_sizes, int n_in,
                              void* d_out, int out_size, void* d_ws, size_t ws_size,
                              hipStream_t stream) {
  const float* x            = (const float*)d_in[0];
  const float* centers      = (const float*)d_in[1];
  const float* log_sigma    = (const float*)d_in[2];
  const float* log_max_rate = (const float*)d_in[3];
  float* out = (float*)d_out;

  const uint32_t nblocks = TOTAL_N / ELEMS_PER_BLOCK;  // 40,000
  popenc_kernel<<<dim3(nblocks), dim3(256), 0, stream>>>(
      x, centers, log_sigma, log_max_rate, out);
}

// Round 3
// 155.621 us; speedup vs baseline: 1.0105x; 1.0105x over previous
//
#include <hip/hip_runtime.h>
#include <math.h>

// PopulationEncoder: spikes[b,f,n,t] = (u[b,f,n,t] < rate[b,f,n]) ? 1.0f : 0.0f
//   rate = exp(-(x[b,f]-c[n])^2 / (2*sigma^2)) * max_rate / 1000
//   u    = jax.random.uniform(key(1), (64,128,100,100))
//
// JAX (threefry_partitionable) random_bits:
//   bits[p] = y0 ^ y1 of threefry2x32(key=(0,1), counter=(0, p))
// u = (bits>>9) * 2^-23 exactly, so with K = ceil(rate*2^23) (proven bit-exact
// in R2, absmax 0.0):  u < rate  <=>  bits>>9 < K  <=>  bits < (K<<9)
// (K <= ceil(0.1*2^23) so K<<9 < 2^32: no overflow; transform is exact).
//
// R3 changes vs R2 (RNG bits and rate math UNTOUCHED):
//  - __builtin_rotateleft32 -> guaranteed single v_alignbit_b32 per rotate
//  - key schedule hand-specialized for ks0=0, c0=0 (round-1 add is a copy,
//    two x0-injections are +0)
//  - per-row threshold stored pre-shifted (K<<9): drops v_lshrrev per element

#define TOTAL_N 81920000u
#define ELEMS_PER_BLOCK 2048u   // 256 threads x 8 elems (two row-safe quads)

__device__ __forceinline__ void tfr(uint32_t& x0, uint32_t& x1, uint32_t r) {
  x0 += x1;
  x1 = __builtin_rotateleft32(x1, r) ^ x0;  // v_add + v_alignbit + v_xor
}

// Threefry-2x32, 20 rounds, key=(0,1), counter=(0,p); returns y0 ^ y1.
// Specialized: ks0=0, ks1=1, ks2=0x1BD11BDB; c0=0.
__device__ __forceinline__ uint32_t threefry_xor(uint32_t p) {
  const uint32_t ks2 = 0x1BD11BDBu;         // 0x1BD11BDA ^ 0 ^ 1
  const uint32_t x1i = p + 1u;              // c1 + ks1
  uint32_t x0 = x1i;                        // round 1: x0 = 0 + x1
  uint32_t x1 = __builtin_rotateleft32(x1i, 13) ^ x0;
  tfr(x0, x1, 15); tfr(x0, x1, 26); tfr(x0, x1, 6);
  x0 += 1u;  x1 += ks2 + 1u;                // inject ks1 | ks2+1
  tfr(x0, x1, 17); tfr(x0, x1, 29); tfr(x0, x1, 16); tfr(x0, x1, 24);
  x0 += ks2; x1 += 2u;                      // inject ks2 | ks0+2
  tfr(x0, x1, 13); tfr(x0, x1, 15); tfr(x0, x1, 26); tfr(x0, x1, 6);
  /* x0 += ks0 == 0 */ x1 += 4u;            // inject ks0 | ks1+3
  tfr(x0, x1, 17); tfr(x0, x1, 29); tfr(x0, x1, 16); tfr(x0, x1, 24);
  x0 += 1u;  x1 += ks2 + 4u;                // inject ks1 | ks2+4
  tfr(x0, x1, 13); tfr(x0, x1, 15); tfr(x0, x1, 26); tfr(x0, x1, 6);
  x0 += ks2; x1 += 5u;                      // inject ks2 | ks0+5
  return x0 ^ x1;
}

__global__ __launch_bounds__(256) void popenc_kernel(
    const float* __restrict__ x,            // [64,128]
    const float* __restrict__ centers,      // [100]
    const float* __restrict__ log_sigma,    // [1]
    const float* __restrict__ log_max_rate, // [1]
    float* __restrict__ out) {              // [64,128,100,100] flat
  // Block covers elements [B0, B0+2048). row = p/100 = (b*128+f)*100+n.
  __shared__ uint32_t sK9[22];  // (ceil(rate*2^23)) << 9, per row

  const uint32_t B0 = blockIdx.x * ELEMS_PER_BLOCK;
  const uint32_t rowFirst = B0 / 100u;
  const uint32_t rowLast  = (B0 + ELEMS_PER_BLOCK - 1u) / 100u;
  const uint32_t nRows    = rowLast - rowFirst + 1u;  // <= 22
  const uint32_t tid = threadIdx.x;

  if (tid < nRows) {
    const uint32_t row = rowFirst + tid;
    // Replicate reference fp32 op order; exp via double -> correctly-rounded f32.
    const float sigma = (float)exp((double)log_sigma[0]);
    const float mrate = (float)exp((double)log_max_rate[0]);
    const float s2    = __fmul_rn(__fmul_rn(2.0f, sigma), sigma);
    const uint32_t xidx = row / 100u;   // b*128+f
    const uint32_t n    = row % 100u;
    const float d    = __fsub_rn(x[xidx], centers[n]);
    const float num  = __fmul_rn(d, d);
    const float arg  = __fdiv_rn(-num, s2);
    const float resp = (float)exp((double)arg);
    const float fr   = __fdiv_rn(__fmul_rn(resp, mrate), 1000.0f);
    const float rs   = __fmul_rn(fr, 8388608.0f); // * 2^23, exact
    sK9[tid] = ((uint32_t)ceilf(rs)) << 9;
  }
  __syncthreads();

  // Two quads per thread; 4 | 100 so a quad never crosses a row boundary.
  const uint32_t pA = B0 + tid * 4u;
  const uint32_t pB = pA + 1024u;
  const uint32_t KA9 = sK9[(pA / 100u) - rowFirst];
  const uint32_t KB9 = sK9[(pB / 100u) - rowFirst];

  float4 qa, qb;
  qa.x = (threefry_xor(pA + 0u) < KA9) ? 1.0f : 0.0f;
  qa.y = (threefry_xor(pA + 1u) < KA9) ? 1.0f : 0.0f;
  qa.z = (threefry_xor(pA + 2u) < KA9) ? 1.0f : 0.0f;
  qa.w = (threefry_xor(pA + 3u) < KA9) ? 1.0f : 0.0f;
  qb.x = (threefry_xor(pB + 0u) < KB9) ? 1.0f : 0.0f;
  qb.y = (threefry_xor(pB + 1u) < KB9) ? 1.0f : 0.0f;
  qb.z = (threefry_xor(pB + 2u) < KB9) ? 1.0f : 0.0f;
  qb.w = (threefry_xor(pB + 3u) < KB9) ? 1.0f : 0.0f;

  *reinterpret_cast<float4*>(out + pA) = qa;
  *reinterpret_cast<float4*>(out + pB) = qb;
}

extern "C" void kernel_launch(void* const* d_in, const int* in_sizes, int n_in,
                              void* d_out, int out_size, void* d_ws, size_t ws_size,
                              hipStream_t stream) {
  const float* x            = (const float*)d_in[0];
  const float* centers      = (const float*)d_in[1];
  const float* log_sigma    = (const float*)d_in[2];
  const float* log_max_rate = (const float*)d_in[3];
  float* out = (float*)d_out;

  const uint32_t nblocks = TOTAL_N / ELEMS_PER_BLOCK;  // 40,000
  popenc_kernel<<<dim3(nblocks), dim3(256), 0, stream>>>(
      x, centers, log_sigma, log_max_rate, out);
}

// Round 4
// 151.081 us; speedup vs baseline: 1.0408x; 1.0300x over previous
//
#include <hip/hip_runtime.h>
#include <math.h>

// PopulationEncoder: spikes[b,f,n,t] = (u < rate[b,f,n]) ? 1 : 0
//   bits[p] = y0 ^ y1 of threefry2x32(key=(0,1), counter=(0,p))   [JAX partitionable]
//   u = (bits>>9) * 2^-23 exactly;  u < rate  <=>  bits < (ceil(rate*2^23) << 9)
// Proven bit-exact in R2/R3 (absmax 0.0). R4: split threshold precompute into a
// builder kernel (K9 table in d_ws), hot kernel = pure threefry + stores
// (no exp, no LDS, no barrier), 16 elems/thread.

#define TOTAL_N 81920000u
#define NROWS   819200u          // 64*128*100 rows of 100 timesteps
#define ELEMS_PER_BLOCK 4096u    // 256 threads x 16 elems (4 row-safe quads)

__device__ __forceinline__ uint32_t rotl(uint32_t x, uint32_t d) {
  return __builtin_rotateleft32(x, d);
}

// Threefry-2x32, 20 rounds, key=(0,1), counter=(0,p); returns y0 ^ y1.
// Injections written as 3-term adds to encourage v_add3_u32.
__device__ __forceinline__ uint32_t threefry_xor(uint32_t p) {
  const uint32_t ks2 = 0x1BD11BDBu;          // 0x1BD11BDA ^ 0 ^ 1
  const uint32_t a = p + 1u;                 // c1 + ks1
  uint32_t x0 = a;                           // round 1: x0 = (0+0) + (p+1)
  uint32_t x1 = rotl(a, 13) ^ x0;
  x0 += x1; x1 = rotl(x1, 15) ^ x0;
  x0 += x1; x1 = rotl(x1, 26) ^ x0;
  x0 += x1; x1 = rotl(x1, 6)  ^ x0;
  x1 += ks2 + 1u;                            // inject (ks1=1, ks2+1)
  x0 = x0 + 1u + x1;                         // v_add3
  x1 = rotl(x1, 17) ^ x0;
  x0 += x1; x1 = rotl(x1, 29) ^ x0;
  x0 += x1; x1 = rotl(x1, 16) ^ x0;
  x0 += x1; x1 = rotl(x1, 24) ^ x0;
  x1 += 2u;                                  // inject (ks2, ks0+2)
  x0 = x0 + ks2 + x1;
  x1 = rotl(x1, 13) ^ x0;
  x0 += x1; x1 = rotl(x1, 15) ^ x0;
  x0 += x1; x1 = rotl(x1, 26) ^ x0;
  x0 += x1; x1 = rotl(x1, 6)  ^ x0;
  x1 += 4u;                                  // inject (ks0=0, ks1+3)
  x0 += x1;
  x1 = rotl(x1, 17) ^ x0;
  x0 += x1; x1 = rotl(x1, 29) ^ x0;
  x0 += x1; x1 = rotl(x1, 16) ^ x0;
  x0 += x1; x1 = rotl(x1, 24) ^ x0;
  x1 += ks2 + 4u;                            // inject (ks1=1, ks2+4)
  x0 = x0 + 1u + x1;
  x1 = rotl(x1, 13) ^ x0;
  x0 += x1; x1 = rotl(x1, 15) ^ x0;
  x0 += x1; x1 = rotl(x1, 26) ^ x0;
  x0 += x1; x1 = rotl(x1, 6)  ^ x0;
  return (x0 + ks2) ^ (x1 + 5u);             // inject (ks2, ks0+5), fold
}

// ---- builder: K9[row] = ceil(rate*2^23) << 9, exact fp32 op order of reference.
__global__ __launch_bounds__(256) void build_k9(
    const float* __restrict__ x,            // [64,128]
    const float* __restrict__ centers,      // [100]
    const float* __restrict__ log_sigma,
    const float* __restrict__ log_max_rate,
    uint32_t* __restrict__ K9) {            // [819200]
  const uint32_t row = blockIdx.x * 256u + threadIdx.x;
  if (row >= NROWS) return;
  const float sigma = (float)exp((double)log_sigma[0]);
  const float mrate = (float)exp((double)log_max_rate[0]);
  const float s2    = __fmul_rn(__fmul_rn(2.0f, sigma), sigma);
  const uint32_t xidx = row / 100u;   // b*128+f
  const uint32_t n    = row % 100u;
  const float d    = __fsub_rn(x[xidx], centers[n]);
  const float num  = __fmul_rn(d, d);
  const float arg  = __fdiv_rn(-num, s2);
  const float resp = (float)exp((double)arg);
  const float fr   = __fdiv_rn(__fmul_rn(resp, mrate), 1000.0f);
  const float rs   = __fmul_rn(fr, 8388608.0f);   // * 2^23, exact
  K9[row] = ((uint32_t)ceilf(rs)) << 9;
}

// ---- hot kernel (table path): no LDS, no barrier, no transcendentals.
__global__ __launch_bounds__(256) void popenc_tab(
    const uint32_t* __restrict__ K9,
    float* __restrict__ out) {
  const uint32_t t4 = blockIdx.x * ELEMS_PER_BLOCK + threadIdx.x * 4u;
  // Issue all 4 threshold loads early (L1/L2-hot; ~25 adjacent lanes share a row).
  uint32_t k[4];
#pragma unroll
  for (uint32_t q = 0; q < 4u; ++q) k[q] = K9[(t4 + q * 1024u) / 100u];
#pragma unroll
  for (uint32_t q = 0; q < 4u; ++q) {
    const uint32_t p = t4 + q * 1024u;   // quad start; 4|100 -> never crosses a row
    float4 o;
    o.x = (threefry_xor(p + 0u) < k[q]) ? 1.0f : 0.0f;
    o.y = (threefry_xor(p + 1u) < k[q]) ? 1.0f : 0.0f;
    o.z = (threefry_xor(p + 2u) < k[q]) ? 1.0f : 0.0f;
    o.w = (threefry_xor(p + 3u) < k[q]) ? 1.0f : 0.0f;
    *reinterpret_cast<float4*>(out + p) = o;
  }
}

// ---- fallback (ws too small): R3-style in-block thresholds, 4096 elems/block.
__global__ __launch_bounds__(256) void popenc_fb(
    const float* __restrict__ x,
    const float* __restrict__ centers,
    const float* __restrict__ log_sigma,
    const float* __restrict__ log_max_rate,
    float* __restrict__ out) {
  __shared__ uint32_t sK9[44];
  const uint32_t B0 = blockIdx.x * ELEMS_PER_BLOCK;
  const uint32_t rowFirst = B0 / 100u;
  const uint32_t nRows = (B0 + ELEMS_PER_BLOCK - 1u) / 100u - rowFirst + 1u; // <=43
  const uint32_t tid = threadIdx.x;
  if (tid < nRows) {
    const uint32_t row = rowFirst + tid;
    const float sigma = (float)exp((double)log_sigma[0]);
    const float mrate = (float)exp((double)log_max_rate[0]);
    const float s2    = __fmul_rn(__fmul_rn(2.0f, sigma), sigma);
    const float d     = __fsub_rn(x[row / 100u], centers[row % 100u]);
    const float arg   = __fdiv_rn(-__fmul_rn(d, d), s2);
    const float resp  = (float)exp((double)arg);
    const float fr    = __fdiv_rn(__fmul_rn(resp, mrate), 1000.0f);
    sK9[tid] = ((uint32_t)ceilf(__fmul_rn(fr, 8388608.0f))) << 9;
  }
  __syncthreads();
  const uint32_t t4 = B0 + tid * 4u;
#pragma unroll
  for (uint32_t q = 0; q < 4u; ++q) {
    const uint32_t p = t4 + q * 1024u;
    const uint32_t kq = sK9[(p / 100u) - rowFirst];
    float4 o;
    o.x = (threefry_xor(p + 0u) < kq) ? 1.0f : 0.0f;
    o.y = (threefry_xor(p + 1u) < kq) ? 1.0f : 0.0f;
    o.z = (threefry_xor(p + 2u) < kq) ? 1.0f : 0.0f;
    o.w = (threefry_xor(p + 3u) < kq) ? 1.0f : 0.0f;
    *reinterpret_cast<float4*>(out + p) = o;
  }
}

extern "C" void kernel_launch(void* const* d_in, const int* in_sizes, int n_in,
                              void* d_out, int out_size, void* d_ws, size_t ws_size,
                              hipStream_t stream) {
  const float* x            = (const float*)d_in[0];
  const float* centers      = (const float*)d_in[1];
  const float* log_sigma    = (const float*)d_in[2];
  const float* log_max_rate = (const float*)d_in[3];
  float* out = (float*)d_out;

  const uint32_t nblocks = TOTAL_N / ELEMS_PER_BLOCK;  // 20,000
  if (d_ws != nullptr && ws_size >= (size_t)NROWS * 4u) {
    uint32_t* K9 = (uint32_t*)d_ws;
    build_k9<<<dim3(NROWS / 256u), dim3(256), 0, stream>>>(
        x, centers, log_sigma, log_max_rate, K9);
    popenc_tab<<<dim3(nblocks), dim3(256), 0, stream>>>(K9, out);
  } else {
    popenc_fb<<<dim3(nblocks), dim3(256), 0, stream>>>(
        x, centers, log_sigma, log_max_rate, out);
  }
}

// Round 5
// 147.759 us; speedup vs baseline: 1.0642x; 1.0225x over previous
//
#include <hip/hip_runtime.h>
#include <math.h>

// PopulationEncoder: spikes[b,f,n,t] = (u < rate[b,f,n]) ? 1 : 0
//   bits[p] = y0 ^ y1 of threefry2x32(key=(0,1), counter=(0,p))   [JAX partitionable]
//   u = (bits>>9) * 2^-23 exactly;  u < rate  <=>  bits < (ceil(rate*2^23) << 9)
// Bit-exact since R2 (absmax 0.0).
//
// R5: ILP/TLP experiment. threefry in 4-wide lockstep (structural 4-way ILP,
// independent of scheduler window), 8 elems/thread (2 quads) -> 2x wave count
// (320K waves) for TLP. Table path (K9 in d_ws) retained from R4.

#define TOTAL_N 81920000u
#define NROWS   819200u          // 64*128*100 rows of 100 timesteps
#define ELEMS_PER_BLOCK 2048u    // 256 threads x 8 elems (2 row-safe quads)

// Threefry-2x32, 20 rounds, key=(0,1), counters (0, p+e) e=0..3, lockstep.
// Returns (y0 ^ y1) per element.
__device__ __forceinline__ void threefry_xor4(uint32_t p, uint32_t y[4]) {
  const uint32_t ks2 = 0x1BD11BDBu;          // 0x1BD11BDA ^ 0 ^ 1
  uint32_t x0[4], x1[4];
#pragma unroll
  for (int e = 0; e < 4; ++e) {
    const uint32_t a = p + (uint32_t)e + 1u; // c1 + ks1
    x0[e] = a;                               // round 1: x0 = 0 + (p+e+1)
    x1[e] = __builtin_rotateleft32(a, 13) ^ a;
  }

#define TFR4(r)                                                   \
  do {                                                            \
    _Pragma("unroll") for (int e = 0; e < 4; ++e) x0[e] += x1[e]; \
    _Pragma("unroll") for (int e = 0; e < 4; ++e)                 \
        x1[e] = __builtin_rotateleft32(x1[e], (r)) ^ x0[e];       \
  } while (0)

  TFR4(15); TFR4(26); TFR4(6);
#pragma unroll
  for (int e = 0; e < 4; ++e) { x1[e] += ks2 + 1u; x0[e] = x0[e] + 1u + x1[e]; }
  // note: injection add feeds next round's add; rotl source is post-injection x1
#pragma unroll
  for (int e = 0; e < 4; ++e) x1[e] = __builtin_rotateleft32(x1[e], 17) ^ x0[e];
  TFR4(29); TFR4(16); TFR4(24);
#pragma unroll
  for (int e = 0; e < 4; ++e) { x1[e] += 2u; x0[e] = x0[e] + ks2 + x1[e]; }
#pragma unroll
  for (int e = 0; e < 4; ++e) x1[e] = __builtin_rotateleft32(x1[e], 13) ^ x0[e];
  TFR4(15); TFR4(26); TFR4(6);
#pragma unroll
  for (int e = 0; e < 4; ++e) { x1[e] += 4u; x0[e] += x1[e]; }
#pragma unroll
  for (int e = 0; e < 4; ++e) x1[e] = __builtin_rotateleft32(x1[e], 17) ^ x0[e];
  TFR4(29); TFR4(16); TFR4(24);
#pragma unroll
  for (int e = 0; e < 4; ++e) { x1[e] += ks2 + 4u; x0[e] = x0[e] + 1u + x1[e]; }
#pragma unroll
  for (int e = 0; e < 4; ++e) x1[e] = __builtin_rotateleft32(x1[e], 13) ^ x0[e];
  TFR4(15); TFR4(26); TFR4(6);
#pragma unroll
  for (int e = 0; e < 4; ++e) y[e] = (x0[e] + ks2) ^ (x1[e] + 5u);
#undef TFR4
}

// ---- builder: K9[row] = ceil(rate*2^23) << 9, exact fp32 op order of reference.
__global__ __launch_bounds__(256) void build_k9(
    const float* __restrict__ x,            // [64,128]
    const float* __restrict__ centers,      // [100]
    const float* __restrict__ log_sigma,
    const float* __restrict__ log_max_rate,
    uint32_t* __restrict__ K9) {            // [819200]
  const uint32_t row = blockIdx.x * 256u + threadIdx.x;
  if (row >= NROWS) return;
  const float sigma = (float)exp((double)log_sigma[0]);
  const float mrate = (float)exp((double)log_max_rate[0]);
  const float s2    = __fmul_rn(__fmul_rn(2.0f, sigma), sigma);
  const uint32_t xidx = row / 100u;   // b*128+f
  const uint32_t n    = row % 100u;
  const float d    = __fsub_rn(x[xidx], centers[n]);
  const float num  = __fmul_rn(d, d);
  const float arg  = __fdiv_rn(-num, s2);
  const float resp = (float)exp((double)arg);
  const float fr   = __fdiv_rn(__fmul_rn(resp, mrate), 1000.0f);
  const float rs   = __fmul_rn(fr, 8388608.0f);   // * 2^23, exact
  K9[row] = ((uint32_t)ceilf(rs)) << 9;
}

// ---- hot kernel: 2 quads/thread, lockstep-4 threefry, no LDS/barrier/exp.
__global__ __launch_bounds__(256) void popenc_tab(
    const uint32_t* __restrict__ K9,
    float* __restrict__ out) {
  const uint32_t pA = blockIdx.x * ELEMS_PER_BLOCK + threadIdx.x * 4u;
  const uint32_t pB = pA + 1024u;
  const uint32_t kA = K9[pA / 100u];   // quad never crosses a row (4 | 100)
  const uint32_t kB = K9[pB / 100u];

  uint32_t ya[4], yb[4];
  threefry_xor4(pA, ya);
  threefry_xor4(pB, yb);

  float4 oa, ob;
  oa.x = (ya[0] < kA) ? 1.0f : 0.0f;
  oa.y = (ya[1] < kA) ? 1.0f : 0.0f;
  oa.z = (ya[2] < kA) ? 1.0f : 0.0f;
  oa.w = (ya[3] < kA) ? 1.0f : 0.0f;
  ob.x = (yb[0] < kB) ? 1.0f : 0.0f;
  ob.y = (yb[1] < kB) ? 1.0f : 0.0f;
  ob.z = (yb[2] < kB) ? 1.0f : 0.0f;
  ob.w = (yb[3] < kB) ? 1.0f : 0.0f;

  *reinterpret_cast<float4*>(out + pA) = oa;
  *reinterpret_cast<float4*>(out + pB) = ob;
}

// ---- fallback (ws too small): in-block thresholds.
__global__ __launch_bounds__(256) void popenc_fb(
    const float* __restrict__ x,
    const float* __restrict__ centers,
    const float* __restrict__ log_sigma,
    const float* __restrict__ log_max_rate,
    float* __restrict__ out) {
  __shared__ uint32_t sK9[22];
  const uint32_t B0 = blockIdx.x * ELEMS_PER_BLOCK;
  const uint32_t rowFirst = B0 / 100u;
  const uint32_t nRows = (B0 + ELEMS_PER_BLOCK - 1u) / 100u - rowFirst + 1u; // <=22
  const uint32_t tid = threadIdx.x;
  if (tid < nRows) {
    const uint32_t row = rowFirst + tid;
    const float sigma = (float)exp((double)log_sigma[0]);
    const float mrate = (float)exp((double)log_max_rate[0]);
    const float s2    = __fmul_rn(__fmul_rn(2.0f, sigma), sigma);
    const float d     = __fsub_rn(x[row / 100u], centers[row % 100u]);
    const float arg   = __fdiv_rn(-__fmul_rn(d, d), s2);
    const float resp  = (float)exp((double)arg);
    const float fr    = __fdiv_rn(__fmul_rn(resp, mrate), 1000.0f);
    sK9[tid] = ((uint32_t)ceilf(__fmul_rn(fr, 8388608.0f))) << 9;
  }
  __syncthreads();
  const uint32_t pA = B0 + tid * 4u;
  const uint32_t pB = pA + 1024u;
  const uint32_t kA = sK9[(pA / 100u) - rowFirst];
  const uint32_t kB = sK9[(pB / 100u) - rowFirst];
  uint32_t ya[4], yb[4];
  threefry_xor4(pA, ya);
  threefry_xor4(pB, yb);
  float4 oa, ob;
  oa.x = (ya[0] < kA) ? 1.0f : 0.0f;
  oa.y = (ya[1] < kA) ? 1.0f : 0.0f;
  oa.z = (ya[2] < kA) ? 1.0f : 0.0f;
  oa.w = (ya[3] < kA) ? 1.0f : 0.0f;
  ob.x = (yb[0] < kB) ? 1.0f : 0.0f;
  ob.y = (yb[1] < kB) ? 1.0f : 0.0f;
  ob.z = (yb[2] < kB) ? 1.0f : 0.0f;
  ob.w = (yb[3] < kB) ? 1.0f : 0.0f;
  *reinterpret_cast<float4*>(out + pA) = oa;
  *reinterpret_cast<float4*>(out + pB) = ob;
}

extern "C" void kernel_launch(void* const* d_in, const int* in_sizes, int n_in,
                              void* d_out, int out_size, void* d_ws, size_t ws_size,
                              hipStream_t stream) {
  const float* x            = (const float*)d_in[0];
  const float* centers      = (const float*)d_in[1];
  const float* log_sigma    = (const float*)d_in[2];
  const float* log_max_rate = (const float*)d_in[3];
  float* out = (float*)d_out;

  const uint32_t nblocks = TOTAL_N / ELEMS_PER_BLOCK;  // 40,000
  if (d_ws != nullptr && ws_size >= (size_t)NROWS * 4u) {
    uint32_t* K9 = (uint32_t*)d_ws;
    build_k9<<<dim3(NROWS / 256u), dim3(256), 0, stream>>>(
        x, centers, log_sigma, log_max_rate, K9);
    popenc_tab<<<dim3(nblocks), dim3(256), 0, stream>>>(K9, out);
  } else {
    popenc_fb<<<dim3(nblocks), dim3(256), 0, stream>>>(
        x, centers, log_sigma, log_max_rate, out);
  }
}

// Round 7
// 147.746 us; speedup vs baseline: 1.0643x; 1.0001x over previous
//
#include <hip/hip_runtime.h>
#include <math.h>

// PopulationEncoder: spikes[b,f,n,t] = (u < rate[b,f,n]) ? 1 : 0
//   bits[p] = y0 ^ y1 of threefry2x32(key=(0,1), counter=(0,p))   [JAX partitionable]
//   u = (bits>>9) * 2^-23 exactly;  u < rate  <=>  bits < (ceil(rate*2^23) << 9)
// Bit-exact since R2 (absmax 0.0).
//
// R7 = R6 with compile fix: __builtin_nontemporal_store needs a native vector
// type, not HIP_vector_type -> use ext_vector_type(4) float (same 16B layout).
// Occupancy experiment: 4 elems/thread (single row-safe quad), minimal live
// state, __launch_bounds__(256,8) to force VGPR<=64 (8 waves/SIMD), nontemporal
// output stores (write-once data; keep L2 for the K9 table). 640K waves.

#define TOTAL_N 81920000u
#define NROWS   819200u          // 64*128*100 rows of 100 timesteps

typedef float floatx4 __attribute__((ext_vector_type(4)));

// Threefry-2x32, 20 rounds, key=(0,1), counters (0, p+e) e=0..3, lockstep.
__device__ __forceinline__ void threefry_xor4(uint32_t p, uint32_t y[4]) {
  const uint32_t ks2 = 0x1BD11BDBu;          // 0x1BD11BDA ^ 0 ^ 1
  uint32_t x0[4], x1[4];
#pragma unroll
  for (int e = 0; e < 4; ++e) {
    const uint32_t a = p + (uint32_t)e + 1u; // c1 + ks1
    x0[e] = a;                               // round 1: x0 = 0 + (p+e+1)
    x1[e] = __builtin_rotateleft32(a, 13) ^ a;
  }

#define TFR4(r)                                                   \
  do {                                                            \
    _Pragma("unroll") for (int e = 0; e < 4; ++e) x0[e] += x1[e]; \
    _Pragma("unroll") for (int e = 0; e < 4; ++e)                 \
        x1[e] = __builtin_rotateleft32(x1[e], (r)) ^ x0[e];       \
  } while (0)

  TFR4(15); TFR4(26); TFR4(6);
#pragma unroll
  for (int e = 0; e < 4; ++e) { x1[e] += ks2 + 1u; x0[e] = x0[e] + 1u + x1[e]; }
#pragma unroll
  for (int e = 0; e < 4; ++e) x1[e] = __builtin_rotateleft32(x1[e], 17) ^ x0[e];
  TFR4(29); TFR4(16); TFR4(24);
#pragma unroll
  for (int e = 0; e < 4; ++e) { x1[e] += 2u; x0[e] = x0[e] + ks2 + x1[e]; }
#pragma unroll
  for (int e = 0; e < 4; ++e) x1[e] = __builtin_rotateleft32(x1[e], 13) ^ x0[e];
  TFR4(15); TFR4(26); TFR4(6);
#pragma unroll
  for (int e = 0; e < 4; ++e) { x1[e] += 4u; x0[e] += x1[e]; }
#pragma unroll
  for (int e = 0; e < 4; ++e) x1[e] = __builtin_rotateleft32(x1[e], 17) ^ x0[e];
  TFR4(29); TFR4(16); TFR4(24);
#pragma unroll
  for (int e = 0; e < 4; ++e) { x1[e] += ks2 + 4u; x0[e] = x0[e] + 1u + x1[e]; }
#pragma unroll
  for (int e = 0; e < 4; ++e) x1[e] = __builtin_rotateleft32(x1[e], 13) ^ x0[e];
  TFR4(15); TFR4(26); TFR4(6);
#pragma unroll
  for (int e = 0; e < 4; ++e) y[e] = (x0[e] + ks2) ^ (x1[e] + 5u);
#undef TFR4
}

// ---- builder: K9[row] = ceil(rate*2^23) << 9, exact fp32 op order of reference.
__global__ __launch_bounds__(256) void build_k9(
    const float* __restrict__ x,            // [64,128]
    const float* __restrict__ centers,      // [100]
    const float* __restrict__ log_sigma,
    const float* __restrict__ log_max_rate,
    uint32_t* __restrict__ K9) {            // [819200]
  const uint32_t row = blockIdx.x * 256u + threadIdx.x;
  if (row >= NROWS) return;
  const float sigma = (float)exp((double)log_sigma[0]);
  const float mrate = (float)exp((double)log_max_rate[0]);
  const float s2    = __fmul_rn(__fmul_rn(2.0f, sigma), sigma);
  const uint32_t xidx = row / 100u;   // b*128+f
  const uint32_t n    = row % 100u;
  const float d    = __fsub_rn(x[xidx], centers[n]);
  const float num  = __fmul_rn(d, d);
  const float arg  = __fdiv_rn(-num, s2);
  const float resp = (float)exp((double)arg);
  const float fr   = __fdiv_rn(__fmul_rn(resp, mrate), 1000.0f);
  const float rs   = __fmul_rn(fr, 8388608.0f);   // * 2^23, exact
  K9[row] = ((uint32_t)ceilf(rs)) << 9;
}

// ---- hot kernel: 1 quad/thread, lockstep-4, minimal VGPR, nt stores.
__global__ __launch_bounds__(256, 8) void popenc_tab(
    const uint32_t* __restrict__ K9,
    float* __restrict__ out) {
  const uint32_t p = blockIdx.x * 1024u + threadIdx.x * 4u;
  const uint32_t k = K9[p / 100u];     // quad never crosses a row (4 | 100)

  uint32_t y[4];
  threefry_xor4(p, y);

  floatx4 o;
  o.x = (y[0] < k) ? 1.0f : 0.0f;
  o.y = (y[1] < k) ? 1.0f : 0.0f;
  o.z = (y[2] < k) ? 1.0f : 0.0f;
  o.w = (y[3] < k) ? 1.0f : 0.0f;

  __builtin_nontemporal_store(o, reinterpret_cast<floatx4*>(out + p));
}

// ---- fallback (ws too small): in-block thresholds, 2048 elems/block.
__global__ __launch_bounds__(256) void popenc_fb(
    const float* __restrict__ x,
    const float* __restrict__ centers,
    const float* __restrict__ log_sigma,
    const float* __restrict__ log_max_rate,
    float* __restrict__ out) {
  __shared__ uint32_t sK9[22];
  const uint32_t B0 = blockIdx.x * 2048u;
  const uint32_t rowFirst = B0 / 100u;
  const uint32_t nRows = (B0 + 2047u) / 100u - rowFirst + 1u; // <=22
  const uint32_t tid = threadIdx.x;
  if (tid < nRows) {
    const uint32_t row = rowFirst + tid;
    const float sigma = (float)exp((double)log_sigma[0]);
    const float mrate = (float)exp((double)log_max_rate[0]);
    const float s2    = __fmul_rn(__fmul_rn(2.0f, sigma), sigma);
    const float d     = __fsub_rn(x[row / 100u], centers[row % 100u]);
    const float arg   = __fdiv_rn(-__fmul_rn(d, d), s2);
    const float resp  = (float)exp((double)arg);
    const float fr    = __fdiv_rn(__fmul_rn(resp, mrate), 1000.0f);
    sK9[tid] = ((uint32_t)ceilf(__fmul_rn(fr, 8388608.0f))) << 9;
  }
  __syncthreads();
  const uint32_t pA = B0 + tid * 4u;
  const uint32_t pB = pA + 1024u;
  const uint32_t kA = sK9[(pA / 100u) - rowFirst];
  const uint32_t kB = sK9[(pB / 100u) - rowFirst];
  uint32_t ya[4], yb[4];
  threefry_xor4(pA, ya);
  threefry_xor4(pB, yb);
  float4 oa, ob;
  oa.x = (ya[0] < kA) ? 1.0f : 0.0f;
  oa.y = (ya[1] < kA) ? 1.0f : 0.0f;
  oa.z = (ya[2] < kA) ? 1.0f : 0.0f;
  oa.w = (ya[3] < kA) ? 1.0f : 0.0f;
  ob.x = (yb[0] < kB) ? 1.0f : 0.0f;
  ob.y = (yb[1] < kB) ? 1.0f : 0.0f;
  ob.z = (yb[2] < kB) ? 1.0f : 0.0f;
  ob.w = (yb[3] < kB) ? 1.0f : 0.0f;
  *reinterpret_cast<float4*>(out + pA) = oa;
  *reinterpret_cast<float4*>(out + pB) = ob;
}

extern "C" void kernel_launch(void* const* d_in, const int* in_sizes, int n_in,
                              void* d_out, int out_size, void* d_ws, size_t ws_size,
                              hipStream_t stream) {
  const float* x            = (const float*)d_in[0];
  const float* centers      = (const float*)d_in[1];
  const float* log_sigma    = (const float*)d_in[2];
  const float* log_max_rate = (const float*)d_in[3];
  float* out = (float*)d_out;

  if (d_ws != nullptr && ws_size >= (size_t)NROWS * 4u) {
    uint32_t* K9 = (uint32_t*)d_ws;
    build_k9<<<dim3(NROWS / 256u), dim3(256), 0, stream>>>(
        x, centers, log_sigma, log_max_rate, K9);
    popenc_tab<<<dim3(TOTAL_N / 1024u), dim3(256), 0, stream>>>(K9, out);
  } else {
    popenc_fb<<<dim3(TOTAL_N / 2048u), dim3(256), 0, stream>>>(
        x, centers, log_sigma, log_max_rate, out);
  }
}